// Round 6
// baseline (1040.692 us; speedup 1.0000x reference)
//
#include <hip/hip_runtime.h>
#include <math.h>

#define NN 100000
#define NE 1000000
#define D  64
#define NB_SCAN 391   // ceil(NN/256)

// ================= CSR build (counting sort by dst) =================

__global__ __launch_bounds__(256) void k_hist(
    const int* __restrict__ dst, int* __restrict__ counts, int* __restrict__ rank)
{
    int e = blockIdx.x * 256 + threadIdx.x;
    if (e >= NE) return;
    rank[e] = atomicAdd(&counts[dst[e]], 1);
}

__global__ __launch_bounds__(256) void k_scan1(
    const int* __restrict__ counts, int* __restrict__ row_start, int* __restrict__ bsum)
{
    __shared__ int s[256];
    int t = threadIdx.x;
    int i = blockIdx.x * 256 + t;
    int v = (i < NN) ? counts[i] : 0;
    s[t] = v; __syncthreads();
#pragma unroll
    for (int off = 1; off < 256; off <<= 1) {
        int add = (t >= off) ? s[t - off] : 0;
        __syncthreads();
        s[t] += add;
        __syncthreads();
    }
    if (i < NN) row_start[i] = s[t] - v;       // local exclusive
    if (t == 255) bsum[blockIdx.x] = s[255];   // block total
}

__global__ __launch_bounds__(512) void k_scan2(
    const int* __restrict__ bsum, int* __restrict__ boff, int* __restrict__ row_start)
{
    __shared__ int s[512];
    int t = threadIdx.x;
    int v = (t < NB_SCAN) ? bsum[t] : 0;
    s[t] = v; __syncthreads();
#pragma unroll
    for (int off = 1; off < 512; off <<= 1) {
        int add = (t >= off) ? s[t - off] : 0;
        __syncthreads();
        s[t] += add;
        __syncthreads();
    }
    if (t < NB_SCAN) boff[t] = s[t] - v;       // exclusive block offsets
    if (t == 0) row_start[NN] = NE;
}

__global__ __launch_bounds__(256) void k_scan3(
    int* __restrict__ row_start, const int* __restrict__ boff)
{
    int i = blockIdx.x * 256 + threadIdx.x;
    if (i < NN) row_start[i] += boff[i >> 8];
}

__global__ __launch_bounds__(256) void k_scatter(
    const int* __restrict__ dst, const int* __restrict__ src,
    const int* __restrict__ perm, const int* __restrict__ rank,
    const int* __restrict__ row_start, int4* __restrict__ sorted,
    int* __restrict__ srcS)
{
    int e = blockIdx.x * 256 + threadIdx.x;
    if (e >= NE) return;
    int s = src[e];
    int pos = row_start[dst[e]] + rank[e];
    sorted[pos] = make_int4(s, e, perm[e], 0);
    srcS[pos] = s;          // bare src stream for the h-pull (4 MB vs 16 MB)
}

// ================= pull-based segment sums (no atomics) =================
// wave = node; lane = (edge_slot es=lane>>4, chan4 c4=(lane&15)*4); 16B/lane
// gathers, 4 edges/wave-iter. Index stream is software-pipelined (q_next
// preloaded before consuming q_cur) so consecutive iterations' gathers
// overlap — R5 was serialised on the loop-carried sorted[i] load (3 TB/s).

__global__ __launch_bounds__(256) void pull_pass1(
    const int4* __restrict__ sorted, const int* __restrict__ row_start,
    const float* __restrict__ nfeats, const float* __restrict__ efeats,
    float* __restrict__ hsum0, float* __restrict__ efsP, float* __restrict__ efsN)
{
    int gt = blockIdx.x * 256 + threadIdx.x;
    int w = gt >> 6, lane = gt & 63;
    if (w >= NN) return;
    int es = lane >> 4, c4 = (lane & 15) << 2;
    int beg = row_start[w], end = row_start[w + 1];

    float an0 = 0.f, an1 = 0.f, an2 = 0.f, an3 = 0.f;
    float ap0 = 0.f, ap1 = 0.f, ap2 = 0.f, ap3 = 0.f;
    float ag0 = 0.f, ag1 = 0.f, ag2 = 0.f, ag3 = 0.f;
    int i = beg + es;
    int4 q = (i < end) ? sorted[i] : make_int4(0, 0, 0, 0);
#pragma unroll 1
    for (; i < end; i += 4) {
        int inext = i + 4;
        int4 qn = (inext < end) ? sorted[inext] : make_int4(0, 0, 0, 0);
        float4 n  = *(const float4*)(nfeats + (size_t)q.x * D + c4);
        float4 ep = *(const float4*)(efeats + (size_t)q.y * D + c4);
        float4 en = *(const float4*)(efeats + (size_t)q.z * D + c4);
        an0 += n.x;  an1 += n.y;  an2 += n.z;  an3 += n.w;
        ap0 += ep.x; ap1 += ep.y; ap2 += ep.z; ap3 += ep.w;
        ag0 += en.x; ag1 += en.y; ag2 += en.z; ag3 += en.w;
        q = qn;
    }
#pragma unroll
    for (int off = 16; off <= 32; off <<= 1) {
        an0 += __shfl_xor(an0, off, 64); an1 += __shfl_xor(an1, off, 64);
        an2 += __shfl_xor(an2, off, 64); an3 += __shfl_xor(an3, off, 64);
        ap0 += __shfl_xor(ap0, off, 64); ap1 += __shfl_xor(ap1, off, 64);
        ap2 += __shfl_xor(ap2, off, 64); ap3 += __shfl_xor(ap3, off, 64);
        ag0 += __shfl_xor(ag0, off, 64); ag1 += __shfl_xor(ag1, off, 64);
        ag2 += __shfl_xor(ag2, off, 64); ag3 += __shfl_xor(ag3, off, 64);
    }
    if (lane < 16) {
        *(float4*)(hsum0 + (size_t)w * D + c4) = make_float4(an0, an1, an2, an3);
        *(float4*)(efsP  + (size_t)w * D + c4) = make_float4(ap0, ap1, ap2, ap3);
        *(float4*)(efsN  + (size_t)w * D + c4) = make_float4(ag0, ag1, ag2, ag3);
    }
}

// dual h-gather: both encodes' h1 rows share the same src index stream.
__global__ __launch_bounds__(256) void pull_h2(
    const int* __restrict__ srcS, const int* __restrict__ row_start,
    const float* __restrict__ hP, const float* __restrict__ hN,
    float* __restrict__ hsumP, float* __restrict__ hsumN)
{
    int gt = blockIdx.x * 256 + threadIdx.x;
    int w = gt >> 6, lane = gt & 63;
    if (w >= NN) return;
    int es = lane >> 4, c4 = (lane & 15) << 2;
    int beg = row_start[w], end = row_start[w + 1];

    float p0 = 0.f, p1 = 0.f, p2 = 0.f, p3 = 0.f;
    float n0 = 0.f, n1 = 0.f, n2 = 0.f, n3 = 0.f;
    int i = beg + es;
    int s = (i < end) ? srcS[i] : 0;
#pragma unroll 1
    for (; i < end; i += 4) {
        int inext = i + 4;
        int sn = (inext < end) ? srcS[inext] : 0;
        float4 vP = *(const float4*)(hP + (size_t)s * D + c4);
        float4 vN = *(const float4*)(hN + (size_t)s * D + c4);
        p0 += vP.x; p1 += vP.y; p2 += vP.z; p3 += vP.w;
        n0 += vN.x; n1 += vN.y; n2 += vN.z; n3 += vN.w;
        s = sn;
    }
#pragma unroll
    for (int off = 16; off <= 32; off <<= 1) {
        p0 += __shfl_xor(p0, off, 64); p1 += __shfl_xor(p1, off, 64);
        p2 += __shfl_xor(p2, off, 64); p3 += __shfl_xor(p3, off, 64);
        n0 += __shfl_xor(n0, off, 64); n1 += __shfl_xor(n1, off, 64);
        n2 += __shfl_xor(n2, off, 64); n3 += __shfl_xor(n3, off, 64);
    }
    if (lane < 16) {
        *(float4*)(hsumP + (size_t)w * D + c4) = make_float4(p0, p1, p2, p3);
        *(float4*)(hsumN + (size_t)w * D + c4) = make_float4(n0, n1, n2, n3);
    }
}

// ================= fused SAGE layer: msg GEMM + apply GEMM =================
// 64 nodes x 64 outs per block, 256 threads, 4x4/thread (rows ty+16*i).
// __launch_bounds__(256,4) caps VGPR at 128; #pragma unroll 1 on k-loops
// prevents the full-unroll register balloon that caused scratch spills (R2:
// VGPR=256, 2.3 GB HBM traffic/dispatch from spill round-trips).
__global__ __launch_bounds__(256, 4) void fused_layer(
    const float* __restrict__ Hsum, const float* __restrict__ Esum,
    const float* __restrict__ Hprev, const int* __restrict__ counts,
    const float* __restrict__ Wmsg, const float* __restrict__ bmsg,
    const float* __restrict__ Wap, const float* __restrict__ bap,
    float* __restrict__ Hout, int do_loss, int is_neg, float* __restrict__ loss_out)
{
    __shared__ __align__(16) float As[64][68];
    __shared__ __align__(16) float Bs[128][68];
    int tid = threadIdx.x;
    int block0 = blockIdx.x * 64;
    int tx = tid & 15, ty = tid >> 4;
    int tx4 = tx << 2;

    // ---- stage Wmsg^T: Bs[k][o] = Wmsg[o*128+k] (coalesced global reads) ----
#pragma unroll 1
    for (int i = 0; i < 32; ++i) {
        int idx = i * 256 + tid;
        Bs[idx & 127][idx >> 7] = Wmsg[idx];
    }

    float acc[4][4] = {};
#pragma unroll
    for (int half = 0; half < 2; ++half) {
        const float* Asrc = half ? Esum : Hsum;
        __syncthreads();            // guards Bs on first pass, As reuse after
#pragma unroll
        for (int g = 0; g < 4; ++g) {
            int idx = g * 256 + tid;
            int node = idx >> 4, c = (idx & 15) << 2;
            int gn = block0 + node;
            float4 v = make_float4(0.f, 0.f, 0.f, 0.f);
            if (gn < NN) v = *(const float4*)(Asrc + (size_t)gn * D + c);
            *(float4*)&As[node][c] = v;
        }
        __syncthreads();
        int hb = half * 64;
#pragma unroll 1
        for (int k0 = 0; k0 < 64; k0 += 4) {
            float a[4][4];
#pragma unroll
            for (int i = 0; i < 4; ++i)
                *(float4*)&a[i][0] = *(const float4*)&As[ty + 16 * i][k0];
#pragma unroll
            for (int kk = 0; kk < 4; ++kk) {
                float4 b = *(const float4*)&Bs[hb + k0 + kk][tx4];
#pragma unroll
                for (int i = 0; i < 4; ++i) {
                    acc[i][0] += a[i][kk] * b.x;
                    acc[i][1] += a[i][kk] * b.y;
                    acc[i][2] += a[i][kk] * b.z;
                    acc[i][3] += a[i][kk] * b.w;
                }
            }
        }
    }

    // ---- msg epilogue: (acc + cnt*bmsg)/max(cnt,1) ----
    float bm[4];
#pragma unroll
    for (int j = 0; j < 4; ++j) bm[j] = bmsg[tx4 + j];
    float msg[4][4];
#pragma unroll
    for (int i = 0; i < 4; ++i) {
        int gn = block0 + ty + 16 * i;
        float c = (gn < NN) ? (float)counts[gn] : 0.f;
        float inv = 1.0f / fmaxf(c, 1.0f);
#pragma unroll
        for (int j = 0; j < 4; ++j) msg[i][j] = (acc[i][j] + c * bm[j]) * inv;
    }

    // ---- phase 2: apply GEMM ----
    __syncthreads();    // all reads of As(Esum)/Bs(Wmsg) complete
#pragma unroll 1
    for (int i = 0; i < 32; ++i) {
        int idx = i * 256 + tid;
        Bs[idx & 127][idx >> 7] = Wap[idx];
    }
#pragma unroll
    for (int i = 0; i < 4; ++i)
        *(float4*)&As[ty + 16 * i][tx4] = make_float4(msg[i][0], msg[i][1], msg[i][2], msg[i][3]);
    __syncthreads();

    float acc2[4][4] = {};
    // msg half (k in [64,128))
#pragma unroll 1
    for (int k0 = 0; k0 < 64; k0 += 4) {
        float a[4][4];
#pragma unroll
        for (int i = 0; i < 4; ++i)
            *(float4*)&a[i][0] = *(const float4*)&As[ty + 16 * i][k0];
#pragma unroll
        for (int kk = 0; kk < 4; ++kk) {
            float4 b = *(const float4*)&Bs[64 + k0 + kk][tx4];
#pragma unroll
            for (int i = 0; i < 4; ++i) {
                acc2[i][0] += a[i][kk] * b.x;
                acc2[i][1] += a[i][kk] * b.y;
                acc2[i][2] += a[i][kk] * b.z;
                acc2[i][3] += a[i][kk] * b.w;
            }
        }
    }
    __syncthreads();
    // Hprev half (k in [0,64))
#pragma unroll
    for (int g = 0; g < 4; ++g) {
        int idx = g * 256 + tid;
        int node = idx >> 4, c = (idx & 15) << 2;
        int gn = block0 + node;
        float4 v = make_float4(0.f, 0.f, 0.f, 0.f);
        if (gn < NN) v = *(const float4*)(Hprev + (size_t)gn * D + c);
        *(float4*)&As[node][c] = v;
    }
    __syncthreads();
#pragma unroll 1
    for (int k0 = 0; k0 < 64; k0 += 4) {
        float a[4][4];
#pragma unroll
        for (int i = 0; i < 4; ++i)
            *(float4*)&a[i][0] = *(const float4*)&As[ty + 16 * i][k0];
#pragma unroll
        for (int kk = 0; kk < 4; ++kk) {
            float4 b = *(const float4*)&Bs[k0 + kk][tx4];
#pragma unroll
            for (int i = 0; i < 4; ++i) {
                acc2[i][0] += a[i][kk] * b.x;
                acc2[i][1] += a[i][kk] * b.y;
                acc2[i][2] += a[i][kk] * b.z;
                acc2[i][3] += a[i][kk] * b.w;
            }
        }
    }

    // ---- epilogue ----
    float ba[4];
#pragma unroll
    for (int j = 0; j < 4; ++j) ba[j] = bap[tx4 + j];
    if (!do_loss) {
#pragma unroll
        for (int i = 0; i < 4; ++i) {
            int gn = block0 + ty + 16 * i;
            if (gn >= NN) continue;
#pragma unroll
            for (int j = 0; j < 4; ++j)
                Hout[(size_t)gn * D + tx4 + j] = fmaxf(acc2[i][j] + ba[j], 0.f);
        }
    } else {
        float lsum = 0.f;
#pragma unroll
        for (int i = 0; i < 4; ++i) {
            int gn = block0 + ty + 16 * i;
            if (gn >= NN) continue;
#pragma unroll
            for (int j = 0; j < 4; ++j) {
                float x = fmaxf(acc2[i][j] + ba[j], 0.f);
                float l = log1pf(expf(-x));   // pos: softplus(-x); neg adds x
                if (is_neg) l += x;
                lsum += l;
            }
        }
#pragma unroll
        for (int off = 32; off; off >>= 1) lsum += __shfl_down(lsum, off, 64);
        if ((tid & 63) == 0)
            unsafeAtomicAdd(loss_out, lsum * (1.0f / 6400000.0f)); // / (N*64)
    }
}

// ================= launch =================
extern "C" void kernel_launch(void* const* d_in, const int* in_sizes, int n_in,
                              void* d_out, int out_size, void* d_ws, size_t ws_size,
                              hipStream_t stream) {
    (void)in_sizes; (void)n_in; (void)out_size; (void)ws_size;
    const float* nfeats = (const float*)d_in[0];
    const float* efeats = (const float*)d_in[1];
    const int*   src    = (const int*)d_in[2];
    const int*   dst    = (const int*)d_in[3];
    const int*   perm   = (const int*)d_in[4];
    const float* Wmsg0  = (const float*)d_in[5];
    const float* bmsg0  = (const float*)d_in[6];
    const float* Wap0   = (const float*)d_in[7];
    const float* bap0   = (const float*)d_in[8];
    const float* Wmsg1  = (const float*)d_in[9];
    const float* bmsg1  = (const float*)d_in[10];
    const float* Wap1   = (const float*)d_in[11];
    const float* bap1   = (const float*)d_in[12];
    float* out = (float*)d_out;

    // ---- workspace layout (16B-aligned chunks; d_ws is ~1 GB) ----
    const size_t NV = (size_t)NN * D;
    char* p = (char*)d_ws;
    int4* sorted   = (int4*)p;               p += (size_t)NE * 16;   // 16 MB
    int*  srcS     = (int*)p;                p += (size_t)NE * 4;    // 4 MB
    int*  rank     = (int*)p;                p += (size_t)NE * 4;    // 4 MB
    int*  counts   = (int*)p;                p += ((NN + 15) & ~15) * 4;
    int*  rowst    = (int*)p;                p += ((NN + 16) & ~15) * 4;
    int*  bsum     = (int*)p;                p += 512 * 4;
    int*  boff     = (int*)p;                p += 512 * 4;
    float* efsP    = (float*)p;              p += NV * 4;            // 25.6 MB
    float* efsN    = (float*)p;              p += NV * 4;
    float* hsum0   = (float*)p;              p += NV * 4;
    float* h1P     = (float*)p;              p += NV * 4;
    float* h1N     = (float*)p;              p += NV * 4;
    float* hsum1P  = (float*)p;              p += NV * 4;
    float* hsum1N  = (float*)p;              p += NV * 4;

    const int EGb = (NE + 255) / 256;        // 3907
    const int PGb = ((size_t)NN * 64 + 255) / 256;  // 25000
    const int NG  = (NN + 63) / 64;          // 1563

    hipMemsetAsync(counts, 0, (size_t)NN * 4, stream);
    hipMemsetAsync(d_out, 0, 4, stream);

    // ---- CSR build ----
    k_hist<<<EGb, 256, 0, stream>>>(dst, counts, rank);
    k_scan1<<<NB_SCAN, 256, 0, stream>>>(counts, rowst, bsum);
    k_scan2<<<1, 512, 0, stream>>>(bsum, boff, rowst);
    k_scan3<<<NB_SCAN, 256, 0, stream>>>(rowst, boff);
    k_scatter<<<EGb, 256, 0, stream>>>(dst, src, perm, rank, rowst, sorted, srcS);

    // ---- all first-layer segment sums in one pass (nfeats, pos ef, neg ef) ----
    pull_pass1<<<PGb, 256, 0, stream>>>(sorted, rowst, nfeats, efeats, hsum0, efsP, efsN);

    // ---- layer 0, both encodes ----
    fused_layer<<<NG, 256, 0, stream>>>(hsum0, efsP, nfeats, counts,
                                        Wmsg0, bmsg0, Wap0, bap0, h1P, 0, 0, nullptr);
    fused_layer<<<NG, 256, 0, stream>>>(hsum0, efsN, nfeats, counts,
                                        Wmsg0, bmsg0, Wap0, bap0, h1N, 0, 0, nullptr);

    // ---- one dual pull for both encodes' h1 ----
    pull_h2<<<PGb, 256, 0, stream>>>(srcS, rowst, h1P, h1N, hsum1P, hsum1N);

    // ---- layer 1 + loss, both encodes ----
    fused_layer<<<NG, 256, 0, stream>>>(hsum1P, efsP, h1P, counts,
                                        Wmsg1, bmsg1, Wap1, bap1, nullptr, 1, 0, out);
    fused_layer<<<NG, 256, 0, stream>>>(hsum1N, efsN, h1N, counts,
                                        Wmsg1, bmsg1, Wap1, bap1, nullptr, 1, 1, out);
}

// Round 7
// 911.565 us; speedup vs baseline: 1.1417x; 1.1417x over previous
//
#include <hip/hip_runtime.h>
#include <math.h>

#define NN 100000
#define NE 1000000
#define D  64
#define NB_SCAN 391   // ceil(NN/256)

// ================= CSR build (counting sort by dst) =================

__global__ __launch_bounds__(256) void k_hist(
    const int* __restrict__ dst, int* __restrict__ counts, int* __restrict__ rank)
{
    int e = blockIdx.x * 256 + threadIdx.x;
    if (e >= NE) return;
    rank[e] = atomicAdd(&counts[dst[e]], 1);
}

__global__ __launch_bounds__(256) void k_scan1(
    const int* __restrict__ counts, int* __restrict__ row_start, int* __restrict__ bsum)
{
    __shared__ int s[256];
    int t = threadIdx.x;
    int i = blockIdx.x * 256 + t;
    int v = (i < NN) ? counts[i] : 0;
    s[t] = v; __syncthreads();
#pragma unroll
    for (int off = 1; off < 256; off <<= 1) {
        int add = (t >= off) ? s[t - off] : 0;
        __syncthreads();
        s[t] += add;
        __syncthreads();
    }
    if (i < NN) row_start[i] = s[t] - v;       // local exclusive
    if (t == 255) bsum[blockIdx.x] = s[255];   // block total
}

__global__ __launch_bounds__(512) void k_scan2(
    const int* __restrict__ bsum, int* __restrict__ boff, int* __restrict__ row_start)
{
    __shared__ int s[512];
    int t = threadIdx.x;
    int v = (t < NB_SCAN) ? bsum[t] : 0;
    s[t] = v; __syncthreads();
#pragma unroll
    for (int off = 1; off < 512; off <<= 1) {
        int add = (t >= off) ? s[t - off] : 0;
        __syncthreads();
        s[t] += add;
        __syncthreads();
    }
    if (t < NB_SCAN) boff[t] = s[t] - v;       // exclusive block offsets
    if (t == 0) row_start[NN] = NE;
}

__global__ __launch_bounds__(256) void k_scan3(
    int* __restrict__ row_start, const int* __restrict__ boff)
{
    int i = blockIdx.x * 256 + threadIdx.x;
    if (i < NN) row_start[i] += boff[i >> 8];
}

__global__ __launch_bounds__(256) void k_scatter(
    const int* __restrict__ dst, const int* __restrict__ src,
    const int* __restrict__ perm, const int* __restrict__ rank,
    const int* __restrict__ row_start, int4* __restrict__ sorted)
{
    int e = blockIdx.x * 256 + threadIdx.x;
    if (e >= NE) return;
    int pos = row_start[dst[e]] + rank[e];
    sorted[pos] = make_int4(src[e], e, perm[e], 0);   // single 16B line-local write
}

// ================= pull-based segment sums (no atomics) =================
// wave = node; lane = (edge_slot es=lane>>4, chan4 c4=(lane&15)*4); 16B/lane
// gathers. ~5.1 TB/s delivered (R6) — near the random-256B-gather ceiling.

__global__ __launch_bounds__(256) void pull_pass1(
    const int4* __restrict__ sorted, const int* __restrict__ row_start,
    const float* __restrict__ nfeats, const float* __restrict__ efeats,
    float* __restrict__ hsum0, float* __restrict__ efsP, float* __restrict__ efsN)
{
    int gt = blockIdx.x * 256 + threadIdx.x;
    int w = gt >> 6, lane = gt & 63;
    if (w >= NN) return;
    int es = lane >> 4, c4 = (lane & 15) << 2;
    int beg = row_start[w], end = row_start[w + 1];

    float an0 = 0.f, an1 = 0.f, an2 = 0.f, an3 = 0.f;
    float ap0 = 0.f, ap1 = 0.f, ap2 = 0.f, ap3 = 0.f;
    float ag0 = 0.f, ag1 = 0.f, ag2 = 0.f, ag3 = 0.f;
    int i = beg + es;
    int4 q = (i < end) ? sorted[i] : make_int4(0, 0, 0, 0);
#pragma unroll 1
    for (; i < end; i += 4) {
        int inext = i + 4;
        int4 qn = (inext < end) ? sorted[inext] : make_int4(0, 0, 0, 0);
        float4 n  = *(const float4*)(nfeats + (size_t)q.x * D + c4);
        float4 ep = *(const float4*)(efeats + (size_t)q.y * D + c4);
        float4 en = *(const float4*)(efeats + (size_t)q.z * D + c4);
        an0 += n.x;  an1 += n.y;  an2 += n.z;  an3 += n.w;
        ap0 += ep.x; ap1 += ep.y; ap2 += ep.z; ap3 += ep.w;
        ag0 += en.x; ag1 += en.y; ag2 += en.z; ag3 += en.w;
        q = qn;
    }
#pragma unroll
    for (int off = 16; off <= 32; off <<= 1) {
        an0 += __shfl_xor(an0, off, 64); an1 += __shfl_xor(an1, off, 64);
        an2 += __shfl_xor(an2, off, 64); an3 += __shfl_xor(an3, off, 64);
        ap0 += __shfl_xor(ap0, off, 64); ap1 += __shfl_xor(ap1, off, 64);
        ap2 += __shfl_xor(ap2, off, 64); ap3 += __shfl_xor(ap3, off, 64);
        ag0 += __shfl_xor(ag0, off, 64); ag1 += __shfl_xor(ag1, off, 64);
        ag2 += __shfl_xor(ag2, off, 64); ag3 += __shfl_xor(ag3, off, 64);
    }
    if (lane < 16) {
        *(float4*)(hsum0 + (size_t)w * D + c4) = make_float4(an0, an1, an2, an3);
        *(float4*)(efsP  + (size_t)w * D + c4) = make_float4(ap0, ap1, ap2, ap3);
        *(float4*)(efsN  + (size_t)w * D + c4) = make_float4(ag0, ag1, ag2, ag3);
    }
}

// dual h-gather from sorted[].x (R6's srcS side-array cost ~64 MB of
// scatter-write amplification — reverted).
__global__ __launch_bounds__(256) void pull_h2(
    const int4* __restrict__ sorted, const int* __restrict__ row_start,
    const float* __restrict__ hP, const float* __restrict__ hN,
    float* __restrict__ hsumP, float* __restrict__ hsumN)
{
    int gt = blockIdx.x * 256 + threadIdx.x;
    int w = gt >> 6, lane = gt & 63;
    if (w >= NN) return;
    int es = lane >> 4, c4 = (lane & 15) << 2;
    int beg = row_start[w], end = row_start[w + 1];

    float p0 = 0.f, p1 = 0.f, p2 = 0.f, p3 = 0.f;
    float n0 = 0.f, n1 = 0.f, n2 = 0.f, n3 = 0.f;
    int i = beg + es;
    int s = (i < end) ? sorted[i].x : 0;
#pragma unroll 1
    for (; i < end; i += 4) {
        int inext = i + 4;
        int sn = (inext < end) ? sorted[inext].x : 0;
        float4 vP = *(const float4*)(hP + (size_t)s * D + c4);
        float4 vN = *(const float4*)(hN + (size_t)s * D + c4);
        p0 += vP.x; p1 += vP.y; p2 += vP.z; p3 += vP.w;
        n0 += vN.x; n1 += vN.y; n2 += vN.z; n3 += vN.w;
        s = sn;
    }
#pragma unroll
    for (int off = 16; off <= 32; off <<= 1) {
        p0 += __shfl_xor(p0, off, 64); p1 += __shfl_xor(p1, off, 64);
        p2 += __shfl_xor(p2, off, 64); p3 += __shfl_xor(p3, off, 64);
        n0 += __shfl_xor(n0, off, 64); n1 += __shfl_xor(n1, off, 64);
        n2 += __shfl_xor(n2, off, 64); n3 += __shfl_xor(n3, off, 64);
    }
    if (lane < 16) {
        *(float4*)(hsumP + (size_t)w * D + c4) = make_float4(p0, p1, p2, p3);
        *(float4*)(hsumN + (size_t)w * D + c4) = make_float4(n0, n1, n2, n3);
    }
}

// ================= merged SAGE layer kernels =================
// gemm_half: 64x64 quarter-GEMM over one 64-k half. unroll-1 + (256,4)
// keeps VGPR<=128 (R2 spill lesson: full unroll -> VGPR 256 -> 2.3 GB spills).

__device__ __forceinline__ void gemm_half(
    float acc[4][4], const float (*As)[68], const float (*Bs)[68],
    int ty, int tx4, int hb)
{
#pragma unroll 1
    for (int k0 = 0; k0 < 64; k0 += 4) {
        float a[4][4];
#pragma unroll
        for (int i = 0; i < 4; ++i)
            *(float4*)&a[i][0] = *(const float4*)&As[ty + 16 * i][k0];
#pragma unroll
        for (int kk = 0; kk < 4; ++kk) {
            float4 b = *(const float4*)&Bs[hb + k0 + kk][tx4];
#pragma unroll
            for (int i = 0; i < 4; ++i) {
                acc[i][0] += a[i][kk] * b.x;
                acc[i][1] += a[i][kk] * b.y;
                acc[i][2] += a[i][kk] * b.z;
                acc[i][3] += a[i][kk] * b.w;
            }
        }
    }
}

#define STAGE_A(SRC) { \
    _Pragma("unroll") \
    for (int g = 0; g < 4; ++g) { \
        int idx = g * 256 + tid; \
        int node = idx >> 4, c = (idx & 15) << 2; \
        int gn = block0 + node; \
        float4 v = make_float4(0.f, 0.f, 0.f, 0.f); \
        if (gn < NN) v = *(const float4*)((SRC) + (size_t)gn * D + c); \
        *(float4*)&As[node][c] = v; } }

#define STAGE_B(W) { \
    _Pragma("unroll 1") \
    for (int i = 0; i < 32; ++i) { \
        int idx = i * 256 + tid; \
        Bs[idx & 127][idx >> 7] = (W)[idx]; } }

#define STORE_MSG(M) { \
    _Pragma("unroll") \
    for (int i = 0; i < 4; ++i) \
        *(float4*)&As[ty + 16 * i][tx4] = make_float4((M)[i][0], (M)[i][1], (M)[i][2], (M)[i][3]); }

// Layer 0, both encodes. Hsum AND Hprev(=nfeats) are shared between P/N, so
// both the msg Hsum-half and the apply Hprev-half are computed once.
// 6 half-GEMMs replace the 8 of two separate dispatches; staging halved.
__global__ __launch_bounds__(256, 4) void fused2_l0(
    const float* __restrict__ Hsum, const float* __restrict__ EsumP,
    const float* __restrict__ EsumN, const float* __restrict__ Hprev,
    const int* __restrict__ counts,
    const float* __restrict__ Wmsg, const float* __restrict__ bmsg,
    const float* __restrict__ Wap, const float* __restrict__ bap,
    float* __restrict__ HoutP, float* __restrict__ HoutN)
{
    __shared__ __align__(16) float As[64][68];    // 17.4 KB
    __shared__ __align__(16) float Bs[128][68];   // 34.8 KB
    int tid = threadIdx.x;
    int block0 = blockIdx.x * 64;
    int tx = tid & 15, ty = tid >> 4;
    int tx4 = tx << 2;

    float cnt[4], inv[4];
#pragma unroll
    for (int i = 0; i < 4; ++i) {
        int gn = block0 + ty + 16 * i;
        cnt[i] = (gn < NN) ? (float)counts[gn] : 0.f;
        inv[i] = 1.0f / fmaxf(cnt[i], 1.0f);
    }
    float bm[4], ba[4];
#pragma unroll
    for (int j = 0; j < 4; ++j) { bm[j] = bmsg[tx4 + j]; ba[j] = bap[tx4 + j]; }

    // ---- msg phase ----
    STAGE_B(Wmsg);
    STAGE_A(Hsum);
    __syncthreads();
    float accb[4][4] = {};
    gemm_half(accb, As, Bs, ty, tx4, 0);          // shared Hsum · Wm[:, :64)
    __syncthreads();
    STAGE_A(EsumP);
    __syncthreads();
    float msgP[4][4];
#pragma unroll
    for (int i = 0; i < 4; ++i)
#pragma unroll
        for (int j = 0; j < 4; ++j) msgP[i][j] = accb[i][j];
    gemm_half(msgP, As, Bs, ty, tx4, 64);
#pragma unroll
    for (int i = 0; i < 4; ++i)
#pragma unroll
        for (int j = 0; j < 4; ++j) msgP[i][j] = (msgP[i][j] + cnt[i] * bm[j]) * inv[i];
    __syncthreads();
    STAGE_A(EsumN);
    __syncthreads();
    gemm_half(accb, As, Bs, ty, tx4, 64);         // accb -> raw msgN
    float msgN[4][4];
#pragma unroll
    for (int i = 0; i < 4; ++i)
#pragma unroll
        for (int j = 0; j < 4; ++j) msgN[i][j] = (accb[i][j] + cnt[i] * bm[j]) * inv[i];

    // ---- apply phase (Hprev shared) ----
    __syncthreads();
    STAGE_B(Wap);
    STAGE_A(Hprev);
    __syncthreads();
    float acc2b[4][4] = {};
    gemm_half(acc2b, As, Bs, ty, tx4, 0);         // shared Hprev · Wap[:, :64)

    __syncthreads();
    STORE_MSG(msgP);
    __syncthreads();
    float acc2[4][4];
#pragma unroll
    for (int i = 0; i < 4; ++i)
#pragma unroll
        for (int j = 0; j < 4; ++j) acc2[i][j] = acc2b[i][j];
    gemm_half(acc2, As, Bs, ty, tx4, 64);
#pragma unroll
    for (int i = 0; i < 4; ++i) {
        int gn = block0 + ty + 16 * i;
        if (gn >= NN) continue;
#pragma unroll
        for (int j = 0; j < 4; ++j)
            HoutP[(size_t)gn * D + tx4 + j] = fmaxf(acc2[i][j] + ba[j], 0.f);
    }

    __syncthreads();
    STORE_MSG(msgN);
    __syncthreads();
#pragma unroll
    for (int i = 0; i < 4; ++i)
#pragma unroll
        for (int j = 0; j < 4; ++j) acc2[i][j] = acc2b[i][j];
    gemm_half(acc2, As, Bs, ty, tx4, 64);
#pragma unroll
    for (int i = 0; i < 4; ++i) {
        int gn = block0 + ty + 16 * i;
        if (gn >= NN) continue;
#pragma unroll
        for (int j = 0; j < 4; ++j)
            HoutN[(size_t)gn * D + tx4 + j] = fmaxf(acc2[i][j] + ba[j], 0.f);
    }
}

// Layer 1 + loss, both encodes. Hsum and Hprev DIFFER per encode here — only
// the W staging, counts/bias loads, and dispatch overhead are shared. Each
// side runs its full 4 half-GEMMs; losses fold into one atomic.
__global__ __launch_bounds__(256, 4) void fused2_l1loss(
    const float* __restrict__ HsumP, const float* __restrict__ HsumN,
    const float* __restrict__ EsumP, const float* __restrict__ EsumN,
    const float* __restrict__ HprevP, const float* __restrict__ HprevN,
    const int* __restrict__ counts,
    const float* __restrict__ Wmsg, const float* __restrict__ bmsg,
    const float* __restrict__ Wap, const float* __restrict__ bap,
    float* __restrict__ loss_out)
{
    __shared__ __align__(16) float As[64][68];
    __shared__ __align__(16) float Bs[128][68];
    int tid = threadIdx.x;
    int block0 = blockIdx.x * 64;
    int tx = tid & 15, ty = tid >> 4;
    int tx4 = tx << 2;

    float cnt[4], inv[4];
#pragma unroll
    for (int i = 0; i < 4; ++i) {
        int gn = block0 + ty + 16 * i;
        cnt[i] = (gn < NN) ? (float)counts[gn] : 0.f;
        inv[i] = 1.0f / fmaxf(cnt[i], 1.0f);
    }
    float bm[4], ba[4];
#pragma unroll
    for (int j = 0; j < 4; ++j) { bm[j] = bmsg[tx4 + j]; ba[j] = bap[tx4 + j]; }

    float lsum = 0.f;
#pragma unroll 1
    for (int side = 0; side < 2; ++side) {
        const float* Hsum  = side ? HsumN  : HsumP;
        const float* Esum  = side ? EsumN  : EsumP;
        const float* Hprev = side ? HprevN : HprevP;

        // msg GEMM
        if (side == 0) { STAGE_B(Wmsg); }        // Bs(Wmsg) persists? No — see below
        else {
            __syncthreads();
            STAGE_B(Wmsg);
        }
        STAGE_A(Hsum);
        __syncthreads();
        float acc[4][4] = {};
        gemm_half(acc, As, Bs, ty, tx4, 0);
        __syncthreads();
        STAGE_A(Esum);
        __syncthreads();
        gemm_half(acc, As, Bs, ty, tx4, 64);
        float msg[4][4];
#pragma unroll
        for (int i = 0; i < 4; ++i)
#pragma unroll
            for (int j = 0; j < 4; ++j) msg[i][j] = (acc[i][j] + cnt[i] * bm[j]) * inv[i];

        // apply GEMM
        __syncthreads();
        STAGE_B(Wap);
        STAGE_A(Hprev);
        __syncthreads();
        float acc2[4][4] = {};
        gemm_half(acc2, As, Bs, ty, tx4, 0);
        __syncthreads();
        STORE_MSG(msg);
        __syncthreads();
        gemm_half(acc2, As, Bs, ty, tx4, 64);

#pragma unroll
        for (int i = 0; i < 4; ++i) {
            int gn = block0 + ty + 16 * i;
            if (gn >= NN) continue;
#pragma unroll
            for (int j = 0; j < 4; ++j) {
                float x = fmaxf(acc2[i][j] + ba[j], 0.f);
                float l = log1pf(expf(-x));      // pos: softplus(-x)
                if (side) l += x;                // neg: softplus(x)
                lsum += l;
            }
        }
    }
#pragma unroll
    for (int off = 32; off; off >>= 1) lsum += __shfl_down(lsum, off, 64);
    if ((tid & 63) == 0)
        unsafeAtomicAdd(loss_out, lsum * (1.0f / 6400000.0f)); // / (N*64)
}

// ================= launch =================
extern "C" void kernel_launch(void* const* d_in, const int* in_sizes, int n_in,
                              void* d_out, int out_size, void* d_ws, size_t ws_size,
                              hipStream_t stream) {
    (void)in_sizes; (void)n_in; (void)out_size; (void)ws_size;
    const float* nfeats = (const float*)d_in[0];
    const float* efeats = (const float*)d_in[1];
    const int*   src    = (const int*)d_in[2];
    const int*   dst    = (const int*)d_in[3];
    const int*   perm   = (const int*)d_in[4];
    const float* Wmsg0  = (const float*)d_in[5];
    const float* bmsg0  = (const float*)d_in[6];
    const float* Wap0   = (const float*)d_in[7];
    const float* bap0   = (const float*)d_in[8];
    const float* Wmsg1  = (const float*)d_in[9];
    const float* bmsg1  = (const float*)d_in[10];
    const float* Wap1   = (const float*)d_in[11];
    const float* bap1   = (const float*)d_in[12];
    float* out = (float*)d_out;

    // ---- workspace layout (16B-aligned chunks; d_ws is ~1 GB) ----
    const size_t NV = (size_t)NN * D;
    char* p = (char*)d_ws;
    int4* sorted   = (int4*)p;               p += (size_t)NE * 16;   // 16 MB
    int*  rank     = (int*)p;                p += (size_t)NE * 4;    // 4 MB
    int*  counts   = (int*)p;                p += ((NN + 15) & ~15) * 4;
    int*  rowst    = (int*)p;                p += ((NN + 16) & ~15) * 4;
    int*  bsum     = (int*)p;                p += 512 * 4;
    int*  boff     = (int*)p;                p += 512 * 4;
    float* efsP    = (float*)p;              p += NV * 4;            // 25.6 MB each
    float* efsN    = (float*)p;              p += NV * 4;
    float* hsum0   = (float*)p;              p += NV * 4;
    float* h1P     = (float*)p;              p += NV * 4;
    float* h1N     = (float*)p;              p += NV * 4;
    float* hsum1P  = (float*)p;              p += NV * 4;
    float* hsum1N  = (float*)p;              p += NV * 4;

    const int EGb = (NE + 255) / 256;        // 3907
    const int PGb = ((size_t)NN * 64 + 255) / 256;  // 25000
    const int NG  = (NN + 63) / 64;          // 1563

    hipMemsetAsync(counts, 0, (size_t)NN * 4, stream);
    hipMemsetAsync(d_out, 0, 4, stream);

    // ---- CSR build ----
    k_hist<<<EGb, 256, 0, stream>>>(dst, counts, rank);
    k_scan1<<<NB_SCAN, 256, 0, stream>>>(counts, rowst, bsum);
    k_scan2<<<1, 512, 0, stream>>>(bsum, boff, rowst);
    k_scan3<<<NB_SCAN, 256, 0, stream>>>(rowst, boff);
    k_scatter<<<EGb, 256, 0, stream>>>(dst, src, perm, rank, rowst, sorted);

    // ---- all first-layer segment sums in one pass ----
    pull_pass1<<<PGb, 256, 0, stream>>>(sorted, rowst, nfeats, efeats, hsum0, efsP, efsN);

    // ---- layer 0 merged (shared Hsum + shared Hprev halves) ----
    fused2_l0<<<NG, 256, 0, stream>>>(hsum0, efsP, efsN, nfeats, counts,
                                      Wmsg0, bmsg0, Wap0, bap0, h1P, h1N);

    // ---- one dual pull for both encodes' h1 ----
    pull_h2<<<PGb, 256, 0, stream>>>(sorted, rowst, h1P, h1N, hsum1P, hsum1N);

    // ---- layer 1 + both losses in one dispatch ----
    fused2_l1loss<<<NG, 256, 0, stream>>>(hsum1P, hsum1N, efsP, efsN, h1P, h1N,
                                          counts, Wmsg1, bmsg1, Wap1, bap1, out);
}